// Round 5
// baseline (193.470 us; speedup 1.0000x reference)
//
#include <hip/hip_runtime.h>
#include <hip/hip_bf16.h>

// IN_DIM=128, H=8, D=16, H*D=128.

typedef short short8 __attribute__((ext_vector_type(8)));
typedef float f32x4 __attribute__((ext_vector_type(4)));

__device__ __forceinline__ unsigned pack_bf16(float a, float b) {
    unsigned ua = __float_as_uint(a), ub = __float_as_uint(b);
    ua += 0x7fffu + ((ua >> 16) & 1u);          // RNE round to bf16
    ub += 0x7fffu + ((ub >> 16) & 1u);
    return (ua >> 16) | (ub & 0xffff0000u);
}

#define ULO(u) __uint_as_float((u) << 16)
#define UHI(u) __uint_as_float((u) & 0xffff0000u)

// ---------------------------------------------------------------------------
// MFMA QKV GEMM. BM=128 rows/block, 4 waves (2x2), each wave 64x64 via
// mfma_f32_16x16x32_bf16. h and WT staged bf16 in LDS, (row&7)<<4 XOR swizzle.
// Outputs: Q fp32 [n][128]; KV rows of 128 uints: K bf16 pairs in uints
// [0,64) (uint c = K cols 2c,2c+1), V in uints [64,128). So head hd's K is
// 8 contiguous uints at row*128 + hd*8; V at +64.
// ---------------------------------------------------------------------------
__global__ __launch_bounds__(256) void qkv_gemm_mfma(
    const float* __restrict__ h,
    const float* __restrict__ W0, const float* __restrict__ b0,
    const float* __restrict__ W1, const float* __restrict__ b1,
    const float* __restrict__ W2, const float* __restrict__ b2,
    float* __restrict__ Qout, unsigned* __restrict__ kvU, int n)
{
    __shared__ __align__(16) unsigned char lds[65536];  // [0,32K): h  [32K,64K): WT
    const int tid  = threadIdx.x;
    const int row0 = blockIdx.x * 128;

    // ---- stage h tile: fp32 -> bf16, swizzled rows of 256B ----
    for (int idx = tid; idx < 128 * 32; idx += 256) {
        const int row = idx >> 5;
        const int c4  = (idx & 31) * 4;
        float4 v = make_float4(0.f, 0.f, 0.f, 0.f);
        if (row0 + row < n)
            v = *(const float4*)(h + (size_t)(row0 + row) * 128 + c4);
        const unsigned off = row * 256 + ((c4 * 2) ^ ((row & 7) << 4));
        *(uint2*)(lds + off) = make_uint2(pack_bf16(v.x, v.y), pack_bf16(v.z, v.w));
    }

    const float* Ws[3] = {W0, W1, W2};
    const float* bs[3] = {b0, b1, b2};

    const int lane = tid & 63, wave = tid >> 6;
    const int wr = wave >> 1, wc = wave & 1;
    const int lr = lane & 15, lg = lane >> 4;
    const int rot = tid & 3;

    for (int w = 0; w < 3; ++w) {
        __syncthreads();
        // ---- stage WT[col][k] bf16 swizzled (transpose of W) ----
        for (int idx = tid; idx < 64 * 32; idx += 256) {
            const int kp = idx >> 5;              // k-pair (2kp, 2kp+1)
            const int c4 = (idx & 31) * 4;
            const float* Wp = Ws[w] + (size_t)(2 * kp) * 128 + c4;
            float4 wa = *(const float4*)Wp;
            float4 wb = *(const float4*)(Wp + 128);
            float a0[4] = {wa.x, wa.y, wa.z, wa.w};
            float a1[4] = {wb.x, wb.y, wb.z, wb.w};
#pragma unroll
            for (int j = 0; j < 4; ++j) {
                const int i   = (j + rot) & 3;    // rotate write order
                const int col = c4 + i;
                const unsigned off = 32768u + col * 256 + ((4 * kp) ^ ((col & 7) << 4));
                *(unsigned*)(lds + off) = pack_bf16(a0[i], a1[i]);
            }
        }
        __syncthreads();

        // ---- MFMA k-loop ----
        f32x4 acc[4][4];
#pragma unroll
        for (int nt = 0; nt < 4; ++nt) {
            const float bv = bs[w][wc * 64 + nt * 16 + lr];
#pragma unroll
            for (int mt = 0; mt < 4; ++mt)
                acc[mt][nt] = (f32x4){bv, bv, bv, bv};
        }
#pragma unroll
        for (int ks = 0; ks < 4; ++ks) {
            const int kb = ks * 64 + lg * 16;
            short8 af[4], bf[4];
#pragma unroll
            for (int mt = 0; mt < 4; ++mt) {
                const int row = wr * 64 + mt * 16 + lr;
                af[mt] = *(const short8*)(lds + row * 256 + (kb ^ ((row & 7) << 4)));
            }
#pragma unroll
            for (int nt = 0; nt < 4; ++nt) {
                const int col = wc * 64 + nt * 16 + lr;
                bf[nt] = *(const short8*)(lds + 32768u + col * 256 + (kb ^ ((col & 7) << 4)));
            }
#pragma unroll
            for (int mt = 0; mt < 4; ++mt)
#pragma unroll
                for (int nt = 0; nt < 4; ++nt)
                    acc[mt][nt] = __builtin_amdgcn_mfma_f32_16x16x32_bf16(
                        af[mt], bf[nt], acc[mt][nt], 0, 0, 0);
        }

        // ---- epilogue: pair adjacent cols via shfl_xor(1) ----
#pragma unroll
        for (int mt = 0; mt < 4; ++mt) {
#pragma unroll
            for (int nt = 0; nt < 4; ++nt) {
                const int col = wc * 64 + nt * 16 + lr;
#pragma unroll
                for (int r = 0; r < 4; ++r) {
                    const int row = row0 + wr * 64 + mt * 16 + lg * 4 + r;
                    const float v  = acc[mt][nt][r];
                    const float vn = __shfl_xor(v, 1);
                    if (!(lane & 1) && row < n) {
                        if (w == 0) {
                            *(float2*)(Qout + (size_t)row * 128 + col) = make_float2(v, vn);
                        } else {
                            // K -> uints [0,64), V -> [64,128)
                            kvU[(size_t)row * 128 + (w == 2 ? 64 : 0) + (col >> 1)] =
                                pack_bf16(v, vn);
                        }
                    }
                }
            }
        }
    }
}

// ---------------------------------------------------------------------------
// CSR build: histogram -> hierarchical exclusive scan -> fill
// ---------------------------------------------------------------------------
__global__ void hist_kernel(const int* __restrict__ dst, int* __restrict__ counts, int e) {
    int i = blockIdx.x * blockDim.x + threadIdx.x;
    if (i < e) atomicAdd(&counts[dst[i]], 1);
}

__global__ void scan_block_sums(const int* __restrict__ counts, int* __restrict__ bsums, int nelem) {
    __shared__ int red[4];
    int i = blockIdx.x * 256 + threadIdx.x;
    int v = (i < nelem) ? counts[i] : 0;
#pragma unroll
    for (int o = 32; o > 0; o >>= 1) v += __shfl_down(v, o, 64);
    if ((threadIdx.x & 63) == 0) red[threadIdx.x >> 6] = v;
    __syncthreads();
    if (threadIdx.x == 0) bsums[blockIdx.x] = red[0] + red[1] + red[2] + red[3];
}

__global__ void scan_exclusive_small(int* __restrict__ bsums, int nb) {
    __shared__ int tmp[256];
    int t = threadIdx.x;
    int v = (t < nb) ? bsums[t] : 0;
    tmp[t] = v;
    __syncthreads();
    for (int o = 1; o < 256; o <<= 1) {
        int u = (t >= o) ? tmp[t - o] : 0;
        __syncthreads();
        tmp[t] += u;
        __syncthreads();
    }
    if (t < nb) bsums[t] = tmp[t] - v;  // exclusive
}

__global__ void scan_final(const int* __restrict__ counts, const int* __restrict__ bsums,
                           int* __restrict__ offsets, int nelem, int e) {
    __shared__ int tmp[256];
    int t = threadIdx.x;
    int i = blockIdx.x * 256 + t;
    int v = (i < nelem) ? counts[i] : 0;
    tmp[t] = v;
    __syncthreads();
    for (int o = 1; o < 256; o <<= 1) {
        int u = (t >= o) ? tmp[t - o] : 0;
        __syncthreads();
        tmp[t] += u;
        __syncthreads();
    }
    if (i < nelem) offsets[i] = bsums[blockIdx.x] + tmp[t] - v;
    if (i == 0 && blockIdx.x == 0) offsets[nelem] = e;
}

__global__ void fill_kernel(const int* __restrict__ src, const int* __restrict__ dst,
                            const int* __restrict__ offsets, int* __restrict__ cursor,
                            int* __restrict__ srcSorted, int e) {
    int i = blockIdx.x * blockDim.x + threadIdx.x;
    if (i < e) {
        int d = dst[i];
        int pos = offsets[d] + atomicAdd(&cursor[d], 1);
        srcSorted[pos] = src[i];
    }
}

// ---------------------------------------------------------------------------
// Gather: one wave per node; lane = slot*8 + head handles (edge slot, head).
// Per batch of 8 edges each lane computes its head's FULL 16-dim score
// in-register (no cross-lane ops, 1 exp per (edge,head)), accumulates
// p*V[16] locally; one 8-slot xor-shuffle reduction per node at the end.
// Scores clamped to [-5,5] before softmax -> segment-max shift unnecessary.
// ---------------------------------------------------------------------------
__global__ __launch_bounds__(256) void mha_node(
    const float* __restrict__ Q, const unsigned* __restrict__ KV,
    const int* __restrict__ offsets, const int* __restrict__ srcSorted,
    float* __restrict__ out, int n)
{
    const int lane = threadIdx.x & 63;
    const int node = (blockIdx.x * blockDim.x + threadIdx.x) >> 6;
    if (node >= n) return;
    const int slot = lane >> 3, head = lane & 7;

    const int beg = offsets[node], end = offsets[node + 1];

    float qr[16];
    {
        const float4* qp = (const float4*)(Q + (size_t)node * 128 + head * 16);
        float4 a = qp[0], b = qp[1], c = qp[2], d = qp[3];
        qr[0]  = a.x; qr[1]  = a.y; qr[2]  = a.z; qr[3]  = a.w;
        qr[4]  = b.x; qr[5]  = b.y; qr[6]  = b.z; qr[7]  = b.w;
        qr[8]  = c.x; qr[9]  = c.y; qr[10] = c.z; qr[11] = c.w;
        qr[12] = d.x; qr[13] = d.y; qr[14] = d.z; qr[15] = d.w;
    }

    float acc[16];
#pragma unroll
    for (int i = 0; i < 16; ++i) acc[i] = 0.f;
    float lsum = 0.f;

    for (int j0 = beg; j0 < end; j0 += 64) {
        const int rem = end - j0;
        const int cnt = rem < 64 ? rem : 64;
        int myS = (lane < cnt) ? srcSorted[j0 + lane] : 0;

        for (int t = 0; t < cnt; t += 8) {
            const int eidx = t + slot;
            const int sl = (eidx < cnt) ? eidx : (cnt - 1);
            const int s = __shfl(myS, sl);

            const uint4* kp = (const uint4*)(KV + (size_t)s * 128 + head * 8);
            uint4 ka = kp[0];    // K dims 0..7   (byte off 0)
            uint4 kb = kp[1];    // K dims 8..15  (16)
            uint4 va = kp[16];   // V dims 0..7   (256)
            uint4 vb = kp[17];   // V dims 8..15  (272)

            float t0 = ULO(ka.x) * qr[0];
            t0 = fmaf(UHI(ka.x), qr[1], t0);
            t0 = fmaf(ULO(ka.y), qr[2], t0);
            t0 = fmaf(UHI(ka.y), qr[3], t0);
            t0 = fmaf(ULO(ka.z), qr[4], t0);
            t0 = fmaf(UHI(ka.z), qr[5], t0);
            t0 = fmaf(ULO(ka.w), qr[6], t0);
            t0 = fmaf(UHI(ka.w), qr[7], t0);
            float t1 = ULO(kb.x) * qr[8];
            t1 = fmaf(UHI(kb.x), qr[9],  t1);
            t1 = fmaf(ULO(kb.y), qr[10], t1);
            t1 = fmaf(UHI(kb.y), qr[11], t1);
            t1 = fmaf(ULO(kb.z), qr[12], t1);
            t1 = fmaf(UHI(kb.z), qr[13], t1);
            t1 = fmaf(ULO(kb.w), qr[14], t1);
            t1 = fmaf(UHI(kb.w), qr[15], t1);

            float sc = fminf(5.f, fmaxf(-5.f, (t0 + t1) * 0.25f));
            float p = (eidx < cnt) ? __expf(sc) : 0.f;
            lsum += p;

            acc[0]  = fmaf(p, ULO(va.x), acc[0]);
            acc[1]  = fmaf(p, UHI(va.x), acc[1]);
            acc[2]  = fmaf(p, ULO(va.y), acc[2]);
            acc[3]  = fmaf(p, UHI(va.y), acc[3]);
            acc[4]  = fmaf(p, ULO(va.z), acc[4]);
            acc[5]  = fmaf(p, UHI(va.z), acc[5]);
            acc[6]  = fmaf(p, ULO(va.w), acc[6]);
            acc[7]  = fmaf(p, UHI(va.w), acc[7]);
            acc[8]  = fmaf(p, ULO(vb.x), acc[8]);
            acc[9]  = fmaf(p, UHI(vb.x), acc[9]);
            acc[10] = fmaf(p, ULO(vb.y), acc[10]);
            acc[11] = fmaf(p, UHI(vb.y), acc[11]);
            acc[12] = fmaf(p, ULO(vb.z), acc[12]);
            acc[13] = fmaf(p, UHI(vb.z), acc[13]);
            acc[14] = fmaf(p, ULO(vb.w), acc[14]);
            acc[15] = fmaf(p, UHI(vb.w), acc[15]);
        }
    }

    // reduce across the 8 slots (lanes head, head+8, ..., head+56)
#pragma unroll
    for (int m = 8; m <= 32; m <<= 1) {
        lsum += __shfl_xor(lsum, m);
#pragma unroll
        for (int i = 0; i < 16; ++i) acc[i] += __shfl_xor(acc[i], m);
    }

    if (slot == 0) {
        const float inv = (lsum > 0.f) ? 1.f / lsum : 0.f;
        float4* op = (float4*)(out + (size_t)node * 128 + head * 16);
        op[0] = make_float4(acc[0] * inv,  acc[1] * inv,  acc[2] * inv,  acc[3] * inv);
        op[1] = make_float4(acc[4] * inv,  acc[5] * inv,  acc[6] * inv,  acc[7] * inv);
        op[2] = make_float4(acc[8] * inv,  acc[9] * inv,  acc[10] * inv, acc[11] * inv);
        op[3] = make_float4(acc[12] * inv, acc[13] * inv, acc[14] * inv, acc[15] * inv);
    }
}

// ---------------------------------------------------------------------------
extern "C" void kernel_launch(void* const* d_in, const int* in_sizes, int n_in,
                              void* d_out, int out_size, void* d_ws, size_t ws_size,
                              hipStream_t stream) {
    const float* h  = (const float*)d_in[0];
    const float* Wq = (const float*)d_in[1];
    const float* bq = (const float*)d_in[2];
    const float* Wk = (const float*)d_in[3];
    const float* bk = (const float*)d_in[4];
    const float* Wv = (const float*)d_in[5];
    const float* bv = (const float*)d_in[6];
    const int*   src = (const int*)d_in[7];
    const int*   dst = (const int*)d_in[8];
    float* out = (float*)d_out;

    const int n = in_sizes[0] / 128;
    const int e = in_sizes[7];
    const int nb = (n + 255) / 256;  // must be <= 256 (n=50000 -> 196)

    char* ws = (char*)d_ws;
    size_t off = 0;
    auto alloc = [&](size_t bytes) {
        char* p = ws + off;
        off = (off + bytes + 255) & ~(size_t)255;
        return p;
    };
    float*    Q        = (float*)alloc((size_t)n * 128 * sizeof(float));
    unsigned* KVb      = (unsigned*)alloc((size_t)n * 128 * sizeof(unsigned));
    int*      counts   = (int*)alloc((size_t)n * sizeof(int));
    int*      offsets  = (int*)alloc((size_t)(n + 1) * sizeof(int));
    int*      bsums    = (int*)alloc((size_t)nb * sizeof(int));
    int*      cursor   = (int*)alloc((size_t)n * sizeof(int));
    int*      srcSorted= (int*)alloc((size_t)e * sizeof(int));
    (void)ws_size; (void)n_in; (void)out_size;

    hipMemsetAsync(counts, 0, (size_t)n * sizeof(int), stream);
    hipMemsetAsync(cursor, 0, (size_t)n * sizeof(int), stream);

    qkv_gemm_mfma<<<(n + 127) / 128, 256, 0, stream>>>(
        h, Wq, bq, Wk, bk, Wv, bv, Q, KVb, n);

    hist_kernel<<<(e + 255) / 256, 256, 0, stream>>>(dst, counts, e);
    scan_block_sums<<<nb, 256, 0, stream>>>(counts, bsums, n);
    scan_exclusive_small<<<1, 256, 0, stream>>>(bsums, nb);
    scan_final<<<nb, 256, 0, stream>>>(counts, bsums, offsets, n, e);
    fill_kernel<<<(e + 255) / 256, 256, 0, stream>>>(src, dst, offsets, cursor, srcSorted, e);

    mha_node<<<((size_t)n * 64 + 255) / 256, 256, 0, stream>>>(
        Q, KVb, offsets, srcSorted, out, n);
}

// Round 6
// 187.211 us; speedup vs baseline: 1.0334x; 1.0334x over previous
//
#include <hip/hip_runtime.h>
#include <hip/hip_bf16.h>

// IN_DIM=128, H=8, D=16, H*D=128.

typedef short short8 __attribute__((ext_vector_type(8)));
typedef float f32x4 __attribute__((ext_vector_type(4)));

__device__ __forceinline__ unsigned pack_bf16(float a, float b) {
    unsigned ua = __float_as_uint(a), ub = __float_as_uint(b);
    ua += 0x7fffu + ((ua >> 16) & 1u);          // RNE round to bf16
    ub += 0x7fffu + ((ub >> 16) & 1u);
    return (ua >> 16) | (ub & 0xffff0000u);
}

#define ULO(u) __uint_as_float((u) << 16)
#define UHI(u) __uint_as_float((u) & 0xffff0000u)

// ---------------------------------------------------------------------------
// prep_w: build swizzled bf16 WT images (one 32KB image per W).
// Image: uint at [col*256 + ((kp*4) ^ ((col&7)<<4))] = pack(W[2kp][col], W[2kp+1][col]).
// GEMM then stages W into LDS as a raw 32KB memcpy.
// Grid: 24 blocks x 256 (blockIdx/8 selects W, %8 selects the idx slice).
// ---------------------------------------------------------------------------
__global__ __launch_bounds__(256) void prep_w(
    const float* __restrict__ W0, const float* __restrict__ W1,
    const float* __restrict__ W2, unsigned char* __restrict__ WTb)
{
    const int w    = blockIdx.x >> 3;
    const int idx  = (blockIdx.x & 7) * 256 + threadIdx.x;  // [0, 2048)
    const float* W = (w == 0) ? W0 : (w == 1) ? W1 : W2;
    unsigned char* wt = WTb + w * 32768;

    const int kp = idx >> 5;           // k-pair (2kp, 2kp+1), [0,64)
    const int c4 = (idx & 31) * 4;     // col group
    const float* Wp = W + (size_t)(2 * kp) * 128 + c4;
    float4 wa = *(const float4*)Wp;
    float4 wb = *(const float4*)(Wp + 128);
    float a0[4] = {wa.x, wa.y, wa.z, wa.w};
    float a1[4] = {wb.x, wb.y, wb.z, wb.w};
#pragma unroll
    for (int i = 0; i < 4; ++i) {
        const int col = c4 + i;
        *(unsigned*)(wt + col * 256 + ((4 * kp) ^ ((col & 7) << 4))) =
            pack_bf16(a0[i], a1[i]);
    }
}

// ---------------------------------------------------------------------------
// prep_h: h fp32 [n][128] -> swizzled bf16 image, 256B per row, zero-padded
// to npad rows. Row image: uint2 at [row*256 + ((c4*2) ^ ((row&7)<<4))]
// holds cols c4..c4+3. Identical to the GEMM's LDS tile image (64 | row0).
// ---------------------------------------------------------------------------
__global__ __launch_bounds__(256) void prep_h(
    const float* __restrict__ h, unsigned char* __restrict__ hb, int n)
{
    const int idx = blockIdx.x * 256 + threadIdx.x;   // [0, npad*32)
    const int row = idx >> 5;
    const int c4  = (idx & 31) * 4;
    float4 v = make_float4(0.f, 0.f, 0.f, 0.f);
    if (row < n) v = *(const float4*)(h + (size_t)row * 128 + c4);
    *(uint2*)(hb + row * 256 + ((c4 * 2) ^ ((row & 7) << 4))) =
        make_uint2(pack_bf16(v.x, v.y), pack_bf16(v.z, v.w));
}

// ---------------------------------------------------------------------------
// MFMA QKV GEMM. BM=64 rows/block, 512 threads = 8 waves (2x4); each wave a
// 32x32 tile = 2x2 frags of mfma_f32_16x16x32_bf16, K-loop 4 steps.
// Staging = raw uint4 memcpy from prebuilt bf16 images. LDS 48KB -> 3 blk/CU.
// Outputs (all bf16 pairs): Qb[row][64] uints (uint c = Q cols 2c,2c+1);
// KVb[row][128] uints, even uint c = K cols (c,c+1), odd c = V cols (c-1,c).
// ---------------------------------------------------------------------------
__global__ __launch_bounds__(512) void qkv_gemm_mfma(
    const unsigned char* __restrict__ hb, const unsigned char* __restrict__ WTb,
    const float* __restrict__ b0, const float* __restrict__ b1,
    const float* __restrict__ b2,
    unsigned* __restrict__ qb, unsigned* __restrict__ kvU)
{
    __shared__ __align__(16) unsigned char lds[49152];  // [0,16K): h  [16K,48K): WT
    const int tid  = threadIdx.x;
    const int row0 = blockIdx.x * 64;

    // stage h tile: 16KB memcpy
    {
        const uint4* src = (const uint4*)(hb + (size_t)row0 * 256);
        uint4* dst = (uint4*)lds;
        dst[tid]       = src[tid];
        dst[tid + 512] = src[tid + 512];
    }

    const float* bs[3] = {b0, b1, b2};

    const int lane = tid & 63, wave = tid >> 6;
    const int wr = wave >> 2, wc = wave & 3;       // 2x4 wave grid
    const int lr = lane & 15, lg = lane >> 4;

    for (int w = 0; w < 3; ++w) {
        __syncthreads();   // protect WT (prev iter) / h-stage (first iter)
        {   // stage WT: 32KB memcpy
            const uint4* src = (const uint4*)(WTb + w * 32768);
            uint4* dst = (uint4*)(lds + 16384);
#pragma unroll
            for (int t = 0; t < 4; ++t) dst[tid + t * 512] = src[tid + t * 512];
        }
        __syncthreads();

        f32x4 acc[2][2];
#pragma unroll
        for (int nt = 0; nt < 2; ++nt) {
            const float bv = bs[w][wc * 32 + nt * 16 + lr];
            acc[0][nt] = (f32x4){bv, bv, bv, bv};
            acc[1][nt] = (f32x4){bv, bv, bv, bv};
        }
#pragma unroll
        for (int ks = 0; ks < 4; ++ks) {
            const int kb = ks * 64 + lg * 16;
            short8 af[2], bf[2];
#pragma unroll
            for (int mt = 0; mt < 2; ++mt) {
                const int row = wr * 32 + mt * 16 + lr;
                af[mt] = *(const short8*)(lds + row * 256 + (kb ^ ((row & 7) << 4)));
            }
#pragma unroll
            for (int nt = 0; nt < 2; ++nt) {
                const int col = wc * 32 + nt * 16 + lr;
                bf[nt] = *(const short8*)(lds + 16384 + col * 256 + (kb ^ ((col & 7) << 4)));
            }
#pragma unroll
            for (int mt = 0; mt < 2; ++mt)
#pragma unroll
                for (int nt = 0; nt < 2; ++nt)
                    acc[mt][nt] = __builtin_amdgcn_mfma_f32_16x16x32_bf16(
                        af[mt], bf[nt], acc[mt][nt], 0, 0, 0);
        }

        // epilogue: pair adjacent cols via shfl_xor(1); even lanes store bf16 pair
#pragma unroll
        for (int mt = 0; mt < 2; ++mt) {
#pragma unroll
            for (int nt = 0; nt < 2; ++nt) {
                const int col = wc * 32 + nt * 16 + lr;
#pragma unroll
                for (int r = 0; r < 4; ++r) {
                    const int row = row0 + wr * 32 + mt * 16 + lg * 4 + r;
                    const float v  = acc[mt][nt][r];
                    const float vn = __shfl_xor(v, 1);
                    if (!(lane & 1)) {
                        const unsigned u = pack_bf16(v, vn);
                        if (w == 0)      qb[(size_t)row * 64 + (col >> 1)] = u;
                        else if (w == 1) kvU[(size_t)row * 128 + col] = u;
                        else             kvU[(size_t)row * 128 + col + 1] = u;
                    }
                }
            }
        }
    }
}

// ---------------------------------------------------------------------------
// CSR build: histogram -> hierarchical exclusive scan -> fill
// ---------------------------------------------------------------------------
__global__ void hist_kernel(const int* __restrict__ dst, int* __restrict__ counts, int e) {
    int i = blockIdx.x * blockDim.x + threadIdx.x;
    if (i < e) atomicAdd(&counts[dst[i]], 1);
}

__global__ void scan_block_sums(const int* __restrict__ counts, int* __restrict__ bsums, int nelem) {
    __shared__ int red[4];
    int i = blockIdx.x * 256 + threadIdx.x;
    int v = (i < nelem) ? counts[i] : 0;
#pragma unroll
    for (int o = 32; o > 0; o >>= 1) v += __shfl_down(v, o, 64);
    if ((threadIdx.x & 63) == 0) red[threadIdx.x >> 6] = v;
    __syncthreads();
    if (threadIdx.x == 0) bsums[blockIdx.x] = red[0] + red[1] + red[2] + red[3];
}

__global__ void scan_exclusive_small(int* __restrict__ bsums, int nb) {
    __shared__ int tmp[256];
    int t = threadIdx.x;
    int v = (t < nb) ? bsums[t] : 0;
    tmp[t] = v;
    __syncthreads();
    for (int o = 1; o < 256; o <<= 1) {
        int u = (t >= o) ? tmp[t - o] : 0;
        __syncthreads();
        tmp[t] += u;
        __syncthreads();
    }
    if (t < nb) bsums[t] = tmp[t] - v;  // exclusive
}

__global__ void scan_final(const int* __restrict__ counts, const int* __restrict__ bsums,
                           int* __restrict__ offsets, int* __restrict__ cur,
                           int nelem, int e) {
    __shared__ int tmp[256];
    int t = threadIdx.x;
    int i = blockIdx.x * 256 + t;
    int v = (i < nelem) ? counts[i] : 0;
    tmp[t] = v;
    __syncthreads();
    for (int o = 1; o < 256; o <<= 1) {
        int u = (t >= o) ? tmp[t - o] : 0;
        __syncthreads();
        tmp[t] += u;
        __syncthreads();
    }
    if (i < nelem) {
        const int ofs = bsums[blockIdx.x] + tmp[t] - v;
        offsets[i] = ofs;
        cur[i] = ofs;          // fill consumes this copy via atomicAdd
    }
    if (i == 0 && blockIdx.x == 0) offsets[nelem] = e;
}

__global__ void fill_kernel(const int* __restrict__ src, const int* __restrict__ dst,
                            int* __restrict__ cur, int* __restrict__ srcSorted, int e) {
    int i = blockIdx.x * blockDim.x + threadIdx.x;
    if (i < e) {
        int pos = atomicAdd(&cur[dst[i]], 1);
        srcSorted[pos] = src[i];
    }
}

// ---------------------------------------------------------------------------
// Gather: one wave per node; lane l owns dims {2l,2l+1}; head = l>>3.
// Per edge: one uint2 (K pair + V pair, bf16), in-pair dot, 3-step 8-lane
// shuffle reduce, exp, 2 fma. Q bf16 packed. Scores clamped to [-5,5] before
// softmax -> segment-max shift unnecessary (shift invariance).
// ---------------------------------------------------------------------------
__global__ __launch_bounds__(256) void mha_node(
    const unsigned* __restrict__ Qb, const uint2* __restrict__ KV,
    const int* __restrict__ offsets, const int* __restrict__ srcSorted,
    float* __restrict__ out, int n)
{
    const int lane = threadIdx.x & 63;
    const int node = (blockIdx.x * blockDim.x + threadIdx.x) >> 6;
    if (node >= n) return;

    const unsigned qu = Qb[(size_t)node * 64 + lane];
    const float qx = ULO(qu), qy = UHI(qu);
    const int beg = offsets[node], end = offsets[node + 1];

    float accx = 0.f, accy = 0.f, lsum = 0.f;

#define EDGE_COMPUTE(kv)                                              \
    {                                                                 \
        float prod = fmaf(ULO((kv).x), qx, UHI((kv).x) * qy);         \
        prod += __shfl_xor(prod, 1);                                  \
        prod += __shfl_xor(prod, 2);                                  \
        prod += __shfl_xor(prod, 4);                                  \
        float sc = fminf(5.f, fmaxf(-5.f, prod * 0.25f));             \
        float p = __expf(sc);                                         \
        lsum += p;                                                    \
        accx = fmaf(p, ULO((kv).y), accx);                            \
        accy = fmaf(p, UHI((kv).y), accy);                            \
    }

    for (int j0 = beg; j0 < end; j0 += 64) {
        const int rem = end - j0;
        const int cnt = rem < 64 ? rem : 64;
        int myS = (lane < cnt) ? srcSorted[j0 + lane] : 0;

        int t = 0;
        for (; t + 8 <= cnt; t += 8) {
            uint2 kv[8];
#pragma unroll
            for (int u = 0; u < 8; ++u) {
                int s = __shfl(myS, t + u);
                kv[u] = KV[(size_t)s * 64 + lane];
            }
#pragma unroll
            for (int u = 0; u < 8; ++u) EDGE_COMPUTE(kv[u]);
        }
        for (; t < cnt; ++t) {
            int s = __shfl(myS, t);
            uint2 kv0 = KV[(size_t)s * 64 + lane];
            EDGE_COMPUTE(kv0);
        }
    }

    float inv = (lsum > 0.f) ? 1.f / lsum : 0.f;
    *(float2*)(out + (size_t)node * 128 + lane * 2) =
        make_float2(accx * inv, accy * inv);
}

// ---------------------------------------------------------------------------
extern "C" void kernel_launch(void* const* d_in, const int* in_sizes, int n_in,
                              void* d_out, int out_size, void* d_ws, size_t ws_size,
                              hipStream_t stream) {
    const float* h  = (const float*)d_in[0];
    const float* Wq = (const float*)d_in[1];
    const float* bq = (const float*)d_in[2];
    const float* Wk = (const float*)d_in[3];
    const float* bk = (const float*)d_in[4];
    const float* Wv = (const float*)d_in[5];
    const float* bv = (const float*)d_in[6];
    const int*   src = (const int*)d_in[7];
    const int*   dst = (const int*)d_in[8];
    float* out = (float*)d_out;

    const int n = in_sizes[0] / 128;
    const int e = in_sizes[7];
    const int nblk = (n + 63) / 64;        // GEMM blocks
    const int npad = nblk * 64;            // padded rows
    const int nb = (n + 255) / 256;        // scan blocks (<=256; n=50000 -> 196)

    char* ws = (char*)d_ws;
    size_t off = 0;
    auto alloc = [&](size_t bytes) {
        char* p = ws + off;
        off = (off + bytes + 255) & ~(size_t)255;
        return p;
    };
    unsigned char* hb   = (unsigned char*)alloc((size_t)npad * 256);
    unsigned char* WTb  = (unsigned char*)alloc(3 * 32768);
    unsigned* Qb        = (unsigned*)alloc((size_t)npad * 64 * 4);
    unsigned* KVb       = (unsigned*)alloc((size_t)npad * 128 * 4);
    int* counts         = (int*)alloc((size_t)n * sizeof(int));
    int* offsets        = (int*)alloc((size_t)(n + 1) * sizeof(int));
    int* cur            = (int*)alloc((size_t)n * sizeof(int));
    int* bsums          = (int*)alloc((size_t)nb * sizeof(int));
    int* srcSorted      = (int*)alloc((size_t)e * sizeof(int));
    (void)ws_size; (void)n_in; (void)out_size;

    hipMemsetAsync(counts, 0, (size_t)n * sizeof(int), stream);

    prep_w<<<24, 256, 0, stream>>>(Wq, Wk, Wv, WTb);
    prep_h<<<(npad * 32) / 256, 256, 0, stream>>>(h, hb, n);

    hist_kernel<<<(e + 255) / 256, 256, 0, stream>>>(dst, counts, e);
    scan_block_sums<<<nb, 256, 0, stream>>>(counts, bsums, n);
    scan_exclusive_small<<<1, 256, 0, stream>>>(bsums, nb);
    scan_final<<<nb, 256, 0, stream>>>(counts, bsums, offsets, cur, n, e);
    fill_kernel<<<(e + 255) / 256, 256, 0, stream>>>(src, dst, cur, srcSorted, e);

    qkv_gemm_mfma<<<nblk, 512, 0, stream>>>(hb, WTb, bq, bk, bv, Qb, KVb);

    mha_node<<<((size_t)n * 64 + 255) / 256, 256, 0, stream>>>(
        Qb, (const uint2*)KVb, offsets, srcSorted, out, n);
}